// Round 4
// baseline (190.700 us; speedup 1.0000x reference)
//
#include <hip/hip_runtime.h>

typedef __bf16 bf16x8 __attribute__((ext_vector_type(8)));
typedef float f32x4 __attribute__((ext_vector_type(4)));

// ---------------------------------------------------------------------------
// Repack all three W [H=128][K] fp32 -> bf16 MFMA B-fragments, one launch.
// Fragment layout: dst[((ks*8 + n)*64 + lane)*8 + e] =
//   bf16(W[n*16 + (lane&15)][ks*32 + (lane>>4)*8 + e])
// ---------------------------------------------------------------------------
__global__ void prep_all_kernel(const float* __restrict__ W0, const float* __restrict__ W1,
                                const float* __restrict__ W2,
                                __bf16* __restrict__ Bf0, __bf16* __restrict__ Bf1,
                                __bf16* __restrict__ Bf2) {
    int t = blockIdx.x * blockDim.x + threadIdx.x;
    const float* W;
    __bf16* dst;
    int K;
    if (t < 1024)      { W = W0; dst = Bf0; K = 64; }
    else if (t < 3072) { W = W1; dst = Bf1; K = 128; t -= 1024; }
    else if (t < 7168) { W = W2; dst = Bf2; K = 256; t -= 3072; }
    else return;
    int lane = t & 63;
    int n = (t >> 6) & 7;
    int ks = t >> 9;
    int row = n * 16 + (lane & 15);
    int k0 = ks * 32 + ((lane >> 4) << 3);
    const float* src = W + (size_t)row * K + k0;
    __bf16* d = dst + (size_t)t * 8;
#pragma unroll
    for (int e = 0; e < 8; ++e) d[e] = (__bf16)src[e];
}

// ---------------------------------------------------------------------------
// One block = 256 threads = 4 waves; block computes 128 rows x 128 cols.
// Each wave: 32 rows (2 M-frags) x 128 cols (8 N-frags), 16x16x32 bf16 MFMA.
// B-frag loaded inside the loop (1 live) to keep register use low.
// Stores: plain cached stores — idx is sorted, so L2 merges neighboring 64B
// sectors across waves into full lines (NT stores defeated this: +30% WRITE).
// ---------------------------------------------------------------------------
template <int K>
__device__ __forceinline__ void run_type(
    const float* __restrict__ x, const __bf16* __restrict__ Bfrag,
    const float* __restrict__ bias, const int* __restrict__ idx,
    float* __restrict__ out, int M, int blk)
{
    constexpr int KSTEPS = K / 32;
    const int lane = threadIdx.x & 63;
    const int wave = threadIdx.x >> 6;
    const int l15 = lane & 15;
    const int kg = lane >> 4;
    const int rowbase = blk * 128 + wave * 32;

    // Hoisted: bias + scatter indices (latency hides under the K-loop MFMAs)
    float bv[8];
#pragma unroll
    for (int n = 0; n < 8; ++n) bv[n] = bias[n * 16 + l15];
    int orow[2][4];
#pragma unroll
    for (int mf = 0; mf < 2; ++mf)
#pragma unroll
        for (int r = 0; r < 4; ++r) {
            int gr = rowbase + mf * 16 + kg * 4 + r;
            orow[mf][r] = idx[gr < M ? gr : M - 1];
        }

    f32x4 acc[2][8] = {};

    int r0 = rowbase + l15;
    int r1 = r0 + 16;
    int r0c = r0 < M ? r0 : M - 1;
    int r1c = r1 < M ? r1 : M - 1;
    const float* a0p = x + (size_t)r0c * K + kg * 8;
    const float* a1p = x + (size_t)r1c * K + kg * 8;
    const bf16x8* bbase = reinterpret_cast<const bf16x8*>(Bfrag) + lane;

#pragma unroll
    for (int ks = 0; ks < KSTEPS; ++ks) {
        bf16x8 a0, a1;
        {
            float4 u0 = *reinterpret_cast<const float4*>(a0p + ks * 32);
            float4 u1 = *reinterpret_cast<const float4*>(a0p + ks * 32 + 4);
            float4 v0 = *reinterpret_cast<const float4*>(a1p + ks * 32);
            float4 v1 = *reinterpret_cast<const float4*>(a1p + ks * 32 + 4);
            a0[0] = (__bf16)u0.x; a0[1] = (__bf16)u0.y; a0[2] = (__bf16)u0.z; a0[3] = (__bf16)u0.w;
            a0[4] = (__bf16)u1.x; a0[5] = (__bf16)u1.y; a0[6] = (__bf16)u1.z; a0[7] = (__bf16)u1.w;
            a1[0] = (__bf16)v0.x; a1[1] = (__bf16)v0.y; a1[2] = (__bf16)v0.z; a1[3] = (__bf16)v0.w;
            a1[4] = (__bf16)v1.x; a1[5] = (__bf16)v1.y; a1[6] = (__bf16)v1.z; a1[7] = (__bf16)v1.w;
        }
#pragma unroll
        for (int n = 0; n < 8; ++n) {
            bf16x8 b = bbase[(ks * 8 + n) * 64];
            acc[0][n] = __builtin_amdgcn_mfma_f32_16x16x32_bf16(a0, b, acc[0][n], 0, 0, 0);
            acc[1][n] = __builtin_amdgcn_mfma_f32_16x16x32_bf16(a1, b, acc[1][n], 0, 0, 0);
        }
    }

    // C/D layout: col = lane&15, row = (lane>>4)*4 + reg
#pragma unroll
    for (int mf = 0; mf < 2; ++mf) {
#pragma unroll
        for (int r = 0; r < 4; ++r) {
            int gr = rowbase + mf * 16 + kg * 4 + r;
            if (gr < M) {
                float* op = out + (size_t)orow[mf][r] * 128 + l15;
#pragma unroll
                for (int n = 0; n < 8; ++n)
                    op[n * 16] = acc[mf][n][r] + bv[n];
            }
        }
    }
}

// Fused: one grid covers all three types. Longest-K type first (better tail).
__global__ __launch_bounds__(256, 4) void fused_linear_kernel(
    const float* __restrict__ x0, const float* __restrict__ x1, const float* __restrict__ x2,
    const __bf16* __restrict__ Bf0, const __bf16* __restrict__ Bf1, const __bf16* __restrict__ Bf2,
    const float* __restrict__ b0, const float* __restrict__ b1, const float* __restrict__ b2,
    const int* __restrict__ idx0, const int* __restrict__ idx1, const int* __restrict__ idx2,
    float* __restrict__ out, int M0, int M1, int M2, int nb2, int nb21)
{
    int b = blockIdx.x;
    if (b < nb2)       run_type<256>(x2, Bf2, b2, idx2, out, M2, b);
    else if (b < nb21) run_type<128>(x1, Bf1, b1, idx1, out, M1, b - nb2);
    else               run_type<64>(x0, Bf0, b0, idx0, out, M0, b - nb21);
}

extern "C" void kernel_launch(void* const* d_in, const int* in_sizes, int n_in,
                              void* d_out, int out_size, void* d_ws, size_t ws_size,
                              hipStream_t stream) {
    const float* x0 = (const float*)d_in[0];
    const float* x1 = (const float*)d_in[1];
    const float* x2 = (const float*)d_in[2];
    const float* W0 = (const float*)d_in[3];
    const float* b0 = (const float*)d_in[4];
    const float* W1 = (const float*)d_in[5];
    const float* b1 = (const float*)d_in[6];
    const float* W2 = (const float*)d_in[7];
    const float* b2 = (const float*)d_in[8];
    const int* idx0 = (const int*)d_in[9];
    const int* idx1 = (const int*)d_in[10];
    const int* idx2 = (const int*)d_in[11];
    float* out = (float*)d_out;

    const int M0 = in_sizes[9];
    const int M1 = in_sizes[10];
    const int M2 = in_sizes[11];

    __bf16* Bf0 = (__bf16*)d_ws;              // K=64:  8192 bf16
    __bf16* Bf1 = Bf0 + 2 * 8 * 64 * 8;       // K=128: 16384 bf16
    __bf16* Bf2 = Bf1 + 4 * 8 * 64 * 8;       // K=256: 32768 bf16

    prep_all_kernel<<<(7168 + 255) / 256, 256, 0, stream>>>(W0, W1, W2, Bf0, Bf1, Bf2);

    const int nb0 = (M0 + 127) / 128;
    const int nb1 = (M1 + 127) / 128;
    const int nb2 = (M2 + 127) / 128;
    fused_linear_kernel<<<nb0 + nb1 + nb2, 256, 0, stream>>>(
        x0, x1, x2, Bf0, Bf1, Bf2, b0, b1, b2, idx0, idx1, idx2,
        out, M0, M1, M2, nb2, nb2 + nb1);
}

// Round 5
// 164.198 us; speedup vs baseline: 1.1614x; 1.1614x over previous
//
#include <hip/hip_runtime.h>

typedef __bf16 bf16x8 __attribute__((ext_vector_type(8)));
typedef float f32x4 __attribute__((ext_vector_type(4)));

// ---------------------------------------------------------------------------
// Repack all three W [H=128][K] fp32 -> bf16 MFMA fragments (used as the "A"
// operand): dst[((ks*8 + hf)*64 + lane)*8 + e] =
//   bf16(W[hf*16 + (lane&15)][ks*32 + (lane>>4)*8 + e])
// ---------------------------------------------------------------------------
__global__ void prep_all_kernel(const float* __restrict__ W0, const float* __restrict__ W1,
                                const float* __restrict__ W2,
                                __bf16* __restrict__ Bf0, __bf16* __restrict__ Bf1,
                                __bf16* __restrict__ Bf2) {
    int t = blockIdx.x * blockDim.x + threadIdx.x;
    const float* W;
    __bf16* dst;
    int K;
    if (t < 1024)      { W = W0; dst = Bf0; K = 64; }
    else if (t < 3072) { W = W1; dst = Bf1; K = 128; t -= 1024; }
    else if (t < 7168) { W = W2; dst = Bf2; K = 256; t -= 3072; }
    else return;
    int lane = t & 63;
    int hf = (t >> 6) & 7;
    int ks = t >> 9;
    int row = hf * 16 + (lane & 15);
    int k0 = ks * 32 + ((lane >> 4) << 3);
    const float* src = W + (size_t)row * K + k0;
    __bf16* d = dst + (size_t)t * 8;
#pragma unroll
    for (int e = 0; e < 8; ++e) d[e] = (__bf16)src[e];
}

// ---------------------------------------------------------------------------
// Swapped-operand MFMA: D = W · x^T.  "A" = W-frag (L2-resident), "B" = x-frag
// (same 16B/lane HBM loads as before). C/D layout (row=kg*4+reg, col=lane&15)
// now means: lane owns ONE output row (m = gr(l15)) and reg 0..3 are four
// CONSECUTIVE h columns -> epilogue is float4 stores (64B contiguous/row/instr)
// instead of 64 scalar dword stores.
// One block = 4 waves; wave computes 32 output rows x 128 cols.
// ---------------------------------------------------------------------------
template <int K>
__device__ __forceinline__ void run_type(
    const float* __restrict__ x, const __bf16* __restrict__ Wfrag,
    const float* __restrict__ bias, const int* __restrict__ idx,
    float* __restrict__ out, int M, int blk)
{
    constexpr int KSTEPS = K / 32;
    const int lane = threadIdx.x & 63;
    const int wave = threadIdx.x >> 6;
    const int l15 = lane & 15;
    const int kg = lane >> 4;
    const int rowbase = blk * 128 + wave * 32;

    // This lane's two source/output rows (mf = 0,1); clamp loads, guard stores.
    const int gr0 = rowbase + l15;
    const int gr1 = gr0 + 16;
    const int r0c = gr0 < M ? gr0 : M - 1;
    const int r1c = gr1 < M ? gr1 : M - 1;
    const int orow0 = idx[r0c];
    const int orow1 = idx[r1c];

    const float* a0p = x + (size_t)r0c * K + kg * 8;
    const float* a1p = x + (size_t)r1c * K + kg * 8;
    const bf16x8* wbase = reinterpret_cast<const bf16x8*>(Wfrag) + lane;

    f32x4 acc[2][8] = {};

#pragma unroll
    for (int ks = 0; ks < KSTEPS; ++ks) {
        bf16x8 xf0, xf1;
        {
            f32x4 u0 = *reinterpret_cast<const f32x4*>(a0p + ks * 32);
            f32x4 u1 = *reinterpret_cast<const f32x4*>(a0p + ks * 32 + 4);
            f32x4 v0 = *reinterpret_cast<const f32x4*>(a1p + ks * 32);
            f32x4 v1 = *reinterpret_cast<const f32x4*>(a1p + ks * 32 + 4);
            xf0[0] = (__bf16)u0[0]; xf0[1] = (__bf16)u0[1]; xf0[2] = (__bf16)u0[2]; xf0[3] = (__bf16)u0[3];
            xf0[4] = (__bf16)u1[0]; xf0[5] = (__bf16)u1[1]; xf0[6] = (__bf16)u1[2]; xf0[7] = (__bf16)u1[3];
            xf1[0] = (__bf16)v0[0]; xf1[1] = (__bf16)v0[1]; xf1[2] = (__bf16)v0[2]; xf1[3] = (__bf16)v0[3];
            xf1[4] = (__bf16)v1[0]; xf1[5] = (__bf16)v1[1]; xf1[6] = (__bf16)v1[2]; xf1[7] = (__bf16)v1[3];
        }
        // burst-preload the 8 W-frags for this k-step (L2-resident, one wait)
        bf16x8 w[8];
#pragma unroll
        for (int hf = 0; hf < 8; ++hf) w[hf] = wbase[(ks * 8 + hf) * 64];
#pragma unroll
        for (int hf = 0; hf < 8; ++hf) {
            acc[0][hf] = __builtin_amdgcn_mfma_f32_16x16x32_bf16(w[hf], xf0, acc[0][hf], 0, 0, 0);
            acc[1][hf] = __builtin_amdgcn_mfma_f32_16x16x32_bf16(w[hf], xf1, acc[1][hf], 0, 0, 0);
        }
    }

    // Epilogue: acc[mf][hf] reg r corresponds to h = hf*16 + kg*4 + r.
#pragma unroll
    for (int hf = 0; hf < 8; ++hf) {
        f32x4 bv = *reinterpret_cast<const f32x4*>(bias + hf * 16 + kg * 4);
        if (gr0 < M) {
            f32x4 v = acc[0][hf] + bv;
            *reinterpret_cast<f32x4*>(out + (size_t)orow0 * 128 + hf * 16 + kg * 4) = v;
        }
        if (gr1 < M) {
            f32x4 v = acc[1][hf] + bv;
            *reinterpret_cast<f32x4*>(out + (size_t)orow1 * 128 + hf * 16 + kg * 4) = v;
        }
    }
}

// Fused: one grid covers all three types. Longest-K type first (better tail).
__global__ __launch_bounds__(256, 3) void fused_linear_kernel(
    const float* __restrict__ x0, const float* __restrict__ x1, const float* __restrict__ x2,
    const __bf16* __restrict__ Bf0, const __bf16* __restrict__ Bf1, const __bf16* __restrict__ Bf2,
    const float* __restrict__ b0, const float* __restrict__ b1, const float* __restrict__ b2,
    const int* __restrict__ idx0, const int* __restrict__ idx1, const int* __restrict__ idx2,
    float* __restrict__ out, int M0, int M1, int M2, int nb2, int nb21)
{
    int b = blockIdx.x;
    if (b < nb2)       run_type<256>(x2, Bf2, b2, idx2, out, M2, b);
    else if (b < nb21) run_type<128>(x1, Bf1, b1, idx1, out, M1, b - nb2);
    else               run_type<64>(x0, Bf0, b0, idx0, out, M0, b - nb21);
}

extern "C" void kernel_launch(void* const* d_in, const int* in_sizes, int n_in,
                              void* d_out, int out_size, void* d_ws, size_t ws_size,
                              hipStream_t stream) {
    const float* x0 = (const float*)d_in[0];
    const float* x1 = (const float*)d_in[1];
    const float* x2 = (const float*)d_in[2];
    const float* W0 = (const float*)d_in[3];
    const float* b0 = (const float*)d_in[4];
    const float* W1 = (const float*)d_in[5];
    const float* b1 = (const float*)d_in[6];
    const float* W2 = (const float*)d_in[7];
    const float* b2 = (const float*)d_in[8];
    const int* idx0 = (const int*)d_in[9];
    const int* idx1 = (const int*)d_in[10];
    const int* idx2 = (const int*)d_in[11];
    float* out = (float*)d_out;

    const int M0 = in_sizes[9];
    const int M1 = in_sizes[10];
    const int M2 = in_sizes[11];

    __bf16* Bf0 = (__bf16*)d_ws;              // K=64:  8192 bf16
    __bf16* Bf1 = Bf0 + 2 * 8 * 64 * 8;       // K=128: 16384 bf16
    __bf16* Bf2 = Bf1 + 4 * 8 * 64 * 8;       // K=256: 32768 bf16

    prep_all_kernel<<<(7168 + 255) / 256, 256, 0, stream>>>(W0, W1, W2, Bf0, Bf1, Bf2);

    const int nb0 = (M0 + 127) / 128;
    const int nb1 = (M1 + 127) / 128;
    const int nb2 = (M2 + 127) / 128;
    fused_linear_kernel<<<nb0 + nb1 + nb2, 256, 0, stream>>>(
        x0, x1, x2, Bf0, Bf1, Bf2, b0, b1, b2, idx0, idx1, idx2,
        out, M0, M1, M2, nb2, nb2 + nb1);
}